// Round 14
// baseline (53.701 us; speedup 1.0000x reference)
//
#include <hip/hip_runtime.h>
#include <hip/hip_bf16.h>

#define RES 7
#define NCH 256

#define TJOBS 6656           // 832 hw64-tiles x 4 cgroups x 2 batches
#define TJOBS_PER_B 3328
#define TJOBS_PER_CG 832
#define TGRID 1024

__device__ __forceinline__ unsigned short f32_to_bf16_rne(float f) {
    unsigned int u = __float_as_uint(f);
    u += 0x7fffu + ((u >> 16) & 1u);
    return (unsigned short)(u >> 16);
}

__device__ __forceinline__ unsigned int pack_bf16x2(float lo, float hi) {
    return (unsigned int)f32_to_bf16_rne(lo) | ((unsigned int)f32_to_bf16_rne(hi) << 16);
}

// ---------------------------------------------------------------------------
// Pass 1 v11: persistent double-buffered DMA pipeline, NCHW fp32 -> NHWC bf16.
// Job = 64 hw x 64 ch. Per iteration: issue global_load_lds for job j+1 into
// buffer B (un-sinkable side-effecting intrinsic -> guaranteed issued BEFORE
// the stores), store job j from buffer A, single barrier drains the
// remainder. Fill latency hides under the store phase (m97 pattern).
// LDS buffer layout: 16 groups (4 channels each) x 260 f32
//   group g: channels c0b+4g..+3 as 4 consecutive 64-float rows (+4 pad).
// One 1KB DMA instr fills one group (lanes 0-15 row0, 16-31 row1, ...).
// ---------------------------------------------------------------------------
struct JobP {
    const float* s;
    unsigned short* d;
    int HW, hw0, c0b;
    bool dma;
};

__device__ __forceinline__ JobP decode_job(
    int j, const float* f0, const float* f1, const float* f2, const float* f3,
    unsigned short* ws)
{
    JobP jp;
    const int b   = (j >= TJOBS_PER_B) ? 1 : 0;
    const int rem = j - b * TJOBS_PER_B;
    const int cg  = rem / TJOBS_PER_CG;
    const int xt  = rem - cg * TJOBS_PER_CG;
    // per-level hw64-tile prefix: f0:625, f1:157, f2:40, f3:10 (total 832)
    const int l    = (xt >= 625) + (xt >= 782) + (xt >= 822);
    const int base = (l == 0) ? 0 : (l == 1) ? 625 : (l == 2) ? 782 : 822;
    const int HW   = (l == 0) ? 40000 : (l == 1) ? 10000 : (l == 2) ? 2500 : 625;
    const float* src = (l == 0) ? f0 : (l == 1) ? f1 : (l == 2) ? f2 : f3;
    const size_t doff = (l == 0) ? 0u : (l == 1) ? 20480000u
                      : (l == 2) ? 25600000u : 26880000u;
    jp.HW  = HW;
    jp.hw0 = (xt - base) * 64;
    jp.c0b = 64 * cg;
    jp.s   = src + (size_t)b * NCH * HW;
    jp.d   = ws + doff + (size_t)b * HW * NCH;
    jp.dma = (jp.hw0 + 64 <= HW) && ((HW & 3) == 0);
    return jp;
}

__device__ __forceinline__ void stage_job(const JobP jp, float* buf, int t)
{
    if (jp.dma) {
        const int w  = t >> 6;
        const int ln = t & 63;
#pragma unroll
        for (int q = 0; q < 2; ++q) {
            const int g = 2 * w + q;                    // group 0..15
            const int c = jp.c0b + 4 * g + (ln >> 4);
            const float* gp = jp.s + (size_t)c * jp.HW + jp.hw0 + (ln & 15) * 4;
            float* lp = buf + g * 260;                  // wave-uniform base
            __builtin_amdgcn_global_load_lds(
                (const __attribute__((address_space(1))) void*)gp,
                (__attribute__((address_space(3))) void*)lp,
                16, 0, 0);
        }
    } else {
        const int cl = t >> 3;          // local channel 0..63
        const int p0 = (t & 7) * 8;     // hw position 0..56
        const int c  = jp.c0b + cl;
#pragma unroll
        for (int i = 0; i < 8; ++i) {
            const int hw = jp.hw0 + p0 + i;
            buf[(cl >> 2) * 260 + (cl & 3) * 64 + p0 + i] =
                (hw < jp.HW) ? jp.s[(size_t)c * jp.HW + hw] : 0.0f;
        }
    }
}

__device__ __forceinline__ void store_job(const JobP jp, const float* buf, int t)
{
#pragma unroll
    for (int it = 0; it < 2; ++it) {
        const int idx = t + 512 * it;   // 0..1023
        const int row = idx >> 4;       // local hw 0..63
        const int u   = idx & 15;       // channel quad 0..15
        const int hw  = jp.hw0 + row;
        if (hw < jp.HW) {
            const float v0 = buf[u * 260 +  0 + row];
            const float v1 = buf[u * 260 + 64 + row];
            const float v2 = buf[u * 260 + 128 + row];
            const float v3 = buf[u * 260 + 192 + row];
            uint2 p;
            p.x = pack_bf16x2(v0, v1);
            p.y = pack_bf16x2(v2, v3);
            *(uint2*)(jp.d + (size_t)hw * NCH + jp.c0b + 4 * u) = p;
        }
    }
}

__global__ __launch_bounds__(512) void transpose_pipe_bf16(
    const float* __restrict__ f0, const float* __restrict__ f1,
    const float* __restrict__ f2, const float* __restrict__ f3,
    unsigned short* __restrict__ ws)
{
    __shared__ float ldsf[2 * 4160];    // two 16x260 f32 buffers (16,640B each)

    const int t = threadIdx.x;

    int j = blockIdx.x;
    JobP cur = decode_job(j, f0, f1, f2, f3, ws);
    int curbuf = 0;
    stage_job(cur, ldsf, t);

    for (;;) {
        const int nj = j + TGRID;
        const bool has = (nj < TJOBS);
        JobP nxt;
        if (has) nxt = decode_job(nj, f0, f1, f2, f3, ws);

        __syncthreads();   // drains cur's fill (vmcnt); prev buffer reads done

        if (has) stage_job(nxt, ldsf + (curbuf ^ 1) * 4160, t);  // overlaps ↓
        store_job(cur, ldsf + curbuf * 4160, t);

        if (!has) break;
        cur = nxt;
        j = nj;
        curbuf ^= 1;
    }
}

// ---------------------------------------------------------------------------
// Pass 2: one block per ROI, 512 threads (8 waves).
// Lane = channel-quad (uint2 = 4 bf16); bins strided over 8 groups.
// ---------------------------------------------------------------------------
__global__ __launch_bounds__(512) void roi_gather_nhwc_bf16(
    const unsigned short* __restrict__ ws,
    const float* __restrict__ boxes, const int* __restrict__ bidx,
    float* __restrict__ out)
{
    __shared__ float lds[49 * 260];

    const int r   = blockIdx.x;
    const int t   = threadIdx.x;
    const int cq  = t & 63;
    const int grp = t >> 6;

    const float bx1 = boxes[r * 4 + 0];
    const float by1 = boxes[r * 4 + 1];
    const float bx2 = boxes[r * 4 + 2];
    const float by2 = boxes[r * 4 + 3];

    const float area = fmaxf(bx2 - bx1, 0.0f) * fmaxf(by2 - by1, 0.0f);
    const float s    = sqrtf(area);
    const float lvlf = floorf(4.0f + log2f(s / 224.0f + 1e-6f));
    const int   lvl  = (int)(fminf(fmaxf(lvlf, 2.0f), 5.0f)) - 2;

    float scale; int H; size_t off;
    if      (lvl == 0) { scale = 0.25f;    H = 200; off = 0u; }
    else if (lvl == 1) { scale = 0.125f;   H = 100; off = 20480000u; }
    else if (lvl == 2) { scale = 0.0625f;  H = 50;  off = 25600000u; }
    else               { scale = 0.03125f; H = 25;  off = 26880000u; }
    const int W = H;

    const int b = bidx[r];
    const unsigned short* __restrict__ feat = ws + off + (size_t)b * H * W * NCH;

    const float x1 = bx1 * scale;
    const float y1 = by1 * scale;
    const float roi_w = fmaxf(bx2 * scale - x1, 1.0f);
    const float roi_h = fmaxf(by2 * scale - y1, 1.0f);
    const float bw = roi_w * (1.0f / RES);
    const float bh = roi_h * (1.0f / RES);

    for (int bin = grp; bin < 49; bin += 8) {
        const int py = bin / 7;
        const int px = bin - py * 7;

        float acc0 = 0.0f, acc1 = 0.0f, acc2 = 0.0f, acc3 = 0.0f;
#pragma unroll
        for (int sy = 0; sy < 2; ++sy) {
            const float pyf = (float)py + ((float)sy + 0.5f) * 0.5f;
            const float ysmp = y1 + pyf * bh;
            const bool  vy   = (ysmp >= -1.0f) && (ysmp <= (float)H);
            const float ycl  = fminf(fmaxf(ysmp, 0.0f), (float)(H - 1));
            const int   y0   = (int)floorf(ycl);
            const int   y1i  = min(y0 + 1, H - 1);
            const float ly   = ycl - (float)y0;
            const float hy   = 1.0f - ly;
#pragma unroll
            for (int sx = 0; sx < 2; ++sx) {
                const float pxf = (float)px + ((float)sx + 0.5f) * 0.5f;
                const float xsmp = x1 + pxf * bw;
                const bool  vx   = (xsmp >= -1.0f) && (xsmp <= (float)W);
                const float xcl  = fminf(fmaxf(xsmp, 0.0f), (float)(W - 1));
                const int   x0   = (int)floorf(xcl);
                const int   x1i  = min(x0 + 1, W - 1);
                const float lx   = xcl - (float)x0;
                const float hx   = 1.0f - lx;

                const float m   = (vy && vx) ? 1.0f : 0.0f;
                const float w00 = m * hy * hx;
                const float w01 = m * hy * lx;
                const float w10 = m * ly * hx;
                const float w11 = m * ly * lx;

                const uint2 u00 = *(const uint2*)(feat + ((size_t)(y0  * W + x0 )) * NCH + 4 * cq);
                const uint2 u01 = *(const uint2*)(feat + ((size_t)(y0  * W + x1i)) * NCH + 4 * cq);
                const uint2 u10 = *(const uint2*)(feat + ((size_t)(y1i * W + x0 )) * NCH + 4 * cq);
                const uint2 u11 = *(const uint2*)(feat + ((size_t)(y1i * W + x1i)) * NCH + 4 * cq);

                acc0 += w00 * __uint_as_float(u00.x << 16)
                      + w01 * __uint_as_float(u01.x << 16)
                      + w10 * __uint_as_float(u10.x << 16)
                      + w11 * __uint_as_float(u11.x << 16);
                acc1 += w00 * __uint_as_float(u00.x & 0xffff0000u)
                      + w01 * __uint_as_float(u01.x & 0xffff0000u)
                      + w10 * __uint_as_float(u10.x & 0xffff0000u)
                      + w11 * __uint_as_float(u11.x & 0xffff0000u);
                acc2 += w00 * __uint_as_float(u00.y << 16)
                      + w01 * __uint_as_float(u01.y << 16)
                      + w10 * __uint_as_float(u10.y << 16)
                      + w11 * __uint_as_float(u11.y << 16);
                acc3 += w00 * __uint_as_float(u00.y & 0xffff0000u)
                      + w01 * __uint_as_float(u01.y & 0xffff0000u)
                      + w10 * __uint_as_float(u10.y & 0xffff0000u)
                      + w11 * __uint_as_float(u11.y & 0xffff0000u);
            }
        }
        float4* dst = (float4*)&lds[bin * 260 + 4 * cq];
        *dst = make_float4(acc0 * 0.25f, acc1 * 0.25f, acc2 * 0.25f, acc3 * 0.25f);
    }

    __syncthreads();

    float* __restrict__ o = out + (size_t)r * (NCH * 49);
    for (int i = t; i < NCH * 49; i += 512) {
        const int ch = i / 49;
        const int bn = i - ch * 49;
        o[i] = lds[bn * 260 + ch];
    }
}

// ---------------------------------------------------------------------------
// Fallback (round-1 kernel) if d_ws is too small for the NHWC bf16 copy.
// ---------------------------------------------------------------------------
__global__ __launch_bounds__(256) void roi_align_fpn_kernel(
    const float* __restrict__ f0, const float* __restrict__ f1,
    const float* __restrict__ f2, const float* __restrict__ f3,
    const float* __restrict__ boxes, const int* __restrict__ bidx,
    float* __restrict__ out)
{
    const int r   = blockIdx.x;
    const int bin = blockIdx.y;
    const int c   = threadIdx.x;
    const int py  = bin / RES;
    const int px  = bin - py * RES;

    const float bx1 = boxes[r * 4 + 0];
    const float by1 = boxes[r * 4 + 1];
    const float bx2 = boxes[r * 4 + 2];
    const float by2 = boxes[r * 4 + 3];

    const float area = fmaxf(bx2 - bx1, 0.0f) * fmaxf(by2 - by1, 0.0f);
    const float s    = sqrtf(area);
    const float lvlf = floorf(4.0f + log2f(s / 224.0f + 1e-6f));
    const int   lvl  = (int)(fminf(fmaxf(lvlf, 2.0f), 5.0f)) - 2;

    const float scales[4] = {0.25f, 0.125f, 0.0625f, 0.03125f};
    const int   Hs[4]     = {200, 100, 50, 25};
    const float* feats[4] = {f0, f1, f2, f3};

    const float scale = scales[lvl];
    const int   H     = Hs[lvl];
    const int   W     = H;
    const float* feat = feats[lvl];

    const int b = bidx[r];

    const float x1 = bx1 * scale;
    const float y1 = by1 * scale;
    const float roi_w = fmaxf(bx2 * scale - x1, 1.0f);
    const float roi_h = fmaxf(by2 * scale - y1, 1.0f);
    const float bw = roi_w * (1.0f / RES);
    const float bh = roi_h * (1.0f / RES);

    const float* __restrict__ fc = feat + (size_t)(b * NCH + c) * H * W;

    float acc = 0.0f;
#pragma unroll
    for (int sy = 0; sy < 2; ++sy) {
        const float pyf = (float)py + ((float)sy + 0.5f) * 0.5f;
        const float ys  = y1 + pyf * bh;
        const bool  vy  = (ys >= -1.0f) && (ys <= (float)H);
        const float ycl = fminf(fmaxf(ys, 0.0f), (float)(H - 1));
        const int   y0  = (int)floorf(ycl);
        const int   y1i = min(y0 + 1, H - 1);
        const float ly  = ycl - (float)y0;
        const float hy  = 1.0f - ly;
#pragma unroll
        for (int sx = 0; sx < 2; ++sx) {
            const float pxf = (float)px + ((float)sx + 0.5f) * 0.5f;
            const float xs  = x1 + pxf * bw;
            const bool  vx  = (xs >= -1.0f) && (xs <= (float)W);
            const float xcl = fminf(fmaxf(xs, 0.0f), (float)(W - 1));
            const int   x0  = (int)floorf(xcl);
            const int   x1i = min(x0 + 1, W - 1);
            const float lx  = xcl - (float)x0;
            const float hx  = 1.0f - lx;

            const float v00 = fc[y0  * W + x0 ];
            const float v01 = fc[y0  * W + x1i];
            const float v10 = fc[y1i * W + x0 ];
            const float v11 = fc[y1i * W + x1i];

            const float v = v00 * (hy * hx) + v01 * (hy * lx)
                          + v10 * (ly * hx) + v11 * (ly * lx);
            if (vy && vx) acc += v;
        }
    }

    out[((size_t)r * NCH + c) * (RES * RES) + bin] = acc * 0.25f;
}

extern "C" void kernel_launch(void* const* d_in, const int* in_sizes, int n_in,
                              void* d_out, int out_size, void* d_ws, size_t ws_size,
                              hipStream_t stream)
{
    const float* f0    = (const float*)d_in[0];
    const float* f1    = (const float*)d_in[1];
    const float* f2    = (const float*)d_in[2];
    const float* f3    = (const float*)d_in[3];
    const float* boxes = (const float*)d_in[4];
    const int*   bidx  = (const int*)d_in[5];
    float* out = (float*)d_out;

    const int R = in_sizes[4] / 4;  // 512 boxes

    const size_t need = 27200000ull * sizeof(unsigned short);  // bf16 NHWC copy

    if (ws_size >= need) {
        unsigned short* ws = (unsigned short*)d_ws;
        transpose_pipe_bf16<<<dim3(TGRID), dim3(512), 0, stream>>>(f0, f1, f2, f3, ws);
        roi_gather_nhwc_bf16<<<dim3(R), dim3(512), 0, stream>>>(ws, boxes, bidx, out);
    } else {
        dim3 grid(R, RES * RES);
        roi_align_fpn_kernel<<<grid, dim3(NCH), 0, stream>>>(f0, f1, f2, f3, boxes, bidx, out);
    }
}